// Round 4
// baseline (81.990 us; speedup 1.0000x reference)
//
#include <hip/hip_runtime.h>
#include <math.h>

#define BB 32
#define NN 2048
#define TB 256            // threads per block (K1, K2)
#define QT 8              // queries per thread in K1 -> 2048 = NN per block
#define RCH 16            // ref chunks (split of the min over refs)
#define MCH (NN / RCH)    // 128 refs per chunk
#define K2_QB (NN / TB)   // 8 query-blocks per (b, role) in K2

// ws layout (floats):
//   part[RCH][2*BB][NN]   partial (|q|^2 + min over chunk of (|r|^2-2q.r)) : 8 MB
//   bsum[5][512]          per-K2-block partial sums (contrib, vis, pt, st, mk)

__device__ __forceinline__ float wred(float v) {
#pragma unroll
    for (int o = 32; o > 0; o >>= 1) v += __shfl_down(v, o, 64);
    return v;
}

// K1: grid (1, BB, 2*RCH); blockIdx.z = rc*2 + role.
// 1024 blocks = 4 blocks/CU = 16 waves/CU for ds_read latency hiding.
// SoA LDS refs in norm form; 8 queries/thread; min3-fused inner loop.
__global__ __launch_bounds__(256) void k1_chamfer(
    const float* __restrict__ pred, const float* __restrict__ tgt,
    float* __restrict__ part)
{
    __shared__ float sa[MCH], sb[MCH], sc[MCH];

    const int tid  = threadIdx.x;
    const int b    = blockIdx.y;
    const int role = blockIdx.z & 1;
    const int rc   = blockIdx.z >> 1;

    const float* q = role ? tgt : pred;
    const float* r = role ? pred : tgt;
    const float* rb = r + ((size_t)b * NN + (size_t)rc * MCH) * 3;

    // Stage refs (threads 0..MCH-1). Invisible refs poisoned far away.
    if (tid < MCH) {
        float rx = rb[3 * tid + 0];
        float ry = rb[3 * tid + 1];
        float rv = rb[3 * tid + 2];
        if (rv != 1.0f) { rx = 1.0e9f; ry = 1.0e9f; }
        sa[tid] = -2.0f * rx;
        sb[tid] = -2.0f * ry;
        sc[tid] = fmaf(rx, rx, ry * ry);
    }
    __syncthreads();

    const float* qb_ = q + (size_t)b * NN * 3;
    float px[QT], py[QT], mn[QT];
#pragma unroll
    for (int j = 0; j < QT; j++) {
        int qi = tid + j * TB;
        px[j] = qb_[3 * qi + 0];
        py[j] = qb_[3 * qi + 1];
        mn[j] = 3.4e38f;
    }

    // 4 refs per iteration: 3 uniform ds_read_b128 (broadcast, conflict-free),
    // then per query 8 fma + 2 min3 -> 2.5 VALU/pair. unroll 4 keeps 12
    // ds_reads in flight ahead of the lgkmcnt waits.
#pragma unroll 4
    for (int m = 0; m < MCH; m += 4) {
        float4 a4 = *(const float4*)&sa[m];
        float4 b4 = *(const float4*)&sb[m];
        float4 c4 = *(const float4*)&sc[m];
#pragma unroll
        for (int j = 0; j < QT; j++) {
            float s0 = fmaf(px[j], a4.x, fmaf(py[j], b4.x, c4.x));
            float s1 = fmaf(px[j], a4.y, fmaf(py[j], b4.y, c4.y));
            float s2 = fmaf(px[j], a4.z, fmaf(py[j], b4.z, c4.z));
            float s3 = fmaf(px[j], a4.w, fmaf(py[j], b4.w, c4.w));
            mn[j] = fminf(fminf(fminf(fminf(s0, s1), s2), s3), mn[j]);
        }
    }

#pragma unroll
    for (int j = 0; j < QT; j++) {
        int qi = tid + j * TB;
        float qn = fmaf(px[j], px[j], py[j] * py[j]);
        part[((size_t)rc * (2 * BB) + role * BB + b) * NN + qi] = qn + mn[j];
    }
}

// K2: combine RCH partials per query (coalesced plane reads), sqrt+mask,
// block-reduce 5 sums, plain store. grid: (K2_QB, BB, 2)
__global__ __launch_bounds__(256) void k2_combine(
    const float* __restrict__ pred, const float* __restrict__ tgt,
    const float* __restrict__ smask, const float* __restrict__ part,
    float* __restrict__ bsum)
{
    __shared__ float sred[5 * 4];
    const int tid  = threadIdx.x;
    const int b    = blockIdx.y;
    const int role = blockIdx.z;
    const int qi   = blockIdx.x * TB + tid;

    float m = 3.4e38f;
#pragma unroll
    for (int rc = 0; rc < RCH; rc++)
        m = fminf(m, part[((size_t)rc * (2 * BB) + role * BB + b) * NN + qi]);

    const float* qp = (role ? tgt : pred) + ((size_t)b * NN + qi) * 3;
    float qvf = (qp[2] == 1.0f) ? 1.0f : 0.0f;
    float contrib = sqrtf(fmaxf(m, 1e-12f)) * qvf;

    float pt = 0.0f, st = 0.0f, mk = 0.0f;
    if (role == 0) {
        float px = qp[0], py = qp[1];
        const float* tp = tgt + ((size_t)b * NN + qi) * 3;
        float vm = (tp[2] == 1.0f) ? 1.0f : 0.0f;
        float dx = px - tp[0], dy = py - tp[1];
        float e2 = fmaf(dx, dx, dy * dy);
        float s0 = smask[((size_t)b * NN + qi) * 2 + 0];
        float s1 = smask[((size_t)b * NN + qi) * 2 + 1];
        float tm = fminf(fmaxf(s0 + s1, 0.0f), 1.0f) * vm;
        pt = e2 * vm;
        st = e2 * tm;
        mk = tm;
    }

    float v[5] = {contrib, qvf, pt, st, mk};
    const int wave = tid >> 6, lane = tid & 63;
#pragma unroll
    for (int i = 0; i < 5; i++) {
        float rv = wred(v[i]);
        if (lane == 0) sred[i * 4 + wave] = rv;
    }
    __syncthreads();
    if (tid < 5) {
        int i = tid;
        float s = sred[i * 4 + 0] + sred[i * 4 + 1] + sred[i * 4 + 2] + sred[i * 4 + 3];
        int slot = (role * BB + b) * K2_QB + blockIdx.x;   // 0..511
        bsum[i * (2 * BB * K2_QB) + slot] = s;
    }
}

// K3: assemble 4 outputs from 5 x 512 block sums. 1 block, 64 threads.
__global__ __launch_bounds__(64) void k3_final(
    const float* __restrict__ bsum, float* __restrict__ out)
{
    const int lane = threadIdx.x;
    const int S = 2 * BB * K2_QB;   // 512

    float ch = 0.0f;
    if (lane < BB) {
        float sp = 0, cp = 0, stt = 0, ct = 0;
#pragma unroll
        for (int x = 0; x < K2_QB; x++) {
            sp  += bsum[0 * S + (0 * BB + lane) * K2_QB + x];
            cp  += bsum[1 * S + (0 * BB + lane) * K2_QB + x];
            stt += bsum[0 * S + (1 * BB + lane) * K2_QB + x];
            ct  += bsum[1 * S + (1 * BB + lane) * K2_QB + x];
        }
        float mp = sp / fmaxf(cp, 1.0f);
        float mt = stt / fmaxf(ct, 1.0f);
        ch = (cp > 0.0f && ct > 0.0f) ? 0.5f * (mp + mt) : 0.0f;
    }
    ch = wred(ch);

    float spt = 0, sst = 0, smk = 0;
    for (int i = lane; i < S; i += 64) {
        spt += bsum[2 * S + i];
        sst += bsum[3 * S + i];
        smk += bsum[4 * S + i];
    }
    spt = wred(spt); sst = wred(sst); smk = wred(smk);

    if (lane == 0) {
        float loss_chamfer = ch / (float)BB;
        const float denom = (float)BB * (float)NN * 2.0f;
        float loss_point = spt / denom;
        float loss_struct = (smk > 0.0f) ? sst / denom : 0.0f;
        out[0] = loss_point + 5.0f * loss_chamfer + 2.0f * loss_struct;
        out[1] = loss_point;
        out[2] = 0.0f;
        out[3] = loss_chamfer;
    }
}

extern "C" void kernel_launch(void* const* d_in, const int* in_sizes, int n_in,
                              void* d_out, int out_size, void* d_ws, size_t ws_size,
                              hipStream_t stream)
{
    const float* pred  = (const float*)d_in[0];
    const float* tgt   = (const float*)d_in[1];
    const float* smask = (const float*)d_in[2];
    float* out = (float*)d_out;
    float* ws  = (float*)d_ws;

    float* part = ws;                                        // 8 MB
    float* bsum = ws + (size_t)RCH * 2 * BB * NN;            // + 10 KB

    k1_chamfer<<<dim3(1, BB, 2 * RCH), TB, 0, stream>>>(pred, tgt, part);
    k2_combine<<<dim3(K2_QB, BB, 2), TB, 0, stream>>>(pred, tgt, smask, part, bsum);
    k3_final<<<1, 64, 0, stream>>>(bsum, out);
}